// Round 2
// baseline (30590.134 us; speedup 1.0000x reference)
//
#include <hip/hip_runtime.h>
#include <cstdint>
#include <cstddef>

#define BATCH   4096
#define IN_DIM  1024
#define HID     16384
#define KSEL    32

// ---------------------------------------------------------------------------
// Kernel 1: encoder GEMM  C[B,H] = X[B,D] @ W_enc[H,D]^T + b_enc
// fp32 vector GEMM, 128x128 tile, BK=16, 256 threads, 8x8 micro-tile.
// v2: double-buffered LDS + register prefetch -> 1 barrier per K-step,
// global-load latency hidden under the 1024-FMA compute phase.
// ---------------------------------------------------------------------------
#define BM 128
#define BN 128
#define BKK 16

__global__ __launch_bounds__(256, 4)
void enc_gemm(const float* __restrict__ X, const float* __restrict__ W,
              const float* __restrict__ bias, float* __restrict__ C)
{
    // +4 pad: keeps 16B alignment (132 = 33*16B/4) and staging stores 2-way (free).
    __shared__ float As[2][BKK][BM + 4];
    __shared__ float Bs[2][BKK][BN + 4];

    const int bn = blockIdx.x;   // HID/128 = 128
    const int bm = blockIdx.y;   // BATCH/128 = 32
    const int t  = threadIdx.x;
    const int tx = t & 15;       // 8 cols each
    const int ty = t >> 4;       // 8 rows each
    const int ar = t >> 2;       // staging row 0..63
    const int ac = (t & 3) << 2; // staging k-offset 0,4,8,12

    float acc[8][8];
#pragma unroll
    for (int i = 0; i < 8; ++i)
#pragma unroll
        for (int j = 0; j < 8; ++j) acc[i][j] = 0.f;

    const float* Xb = X + (size_t)(bm * BM) * IN_DIM;
    const float* Wb = W + (size_t)(bn * BN) * IN_DIM;

    // ---- prologue: stage tile 0 into buffer 0
    {
        const int k0 = 0;
#pragma unroll
        for (int p = 0; p < 2; ++p) {
            const int row = ar + p * 64;
            const float4 va = *(const float4*)(Xb + (size_t)row * IN_DIM + k0 + ac);
            As[0][ac + 0][row] = va.x; As[0][ac + 1][row] = va.y;
            As[0][ac + 2][row] = va.z; As[0][ac + 3][row] = va.w;
            const float4 vb = *(const float4*)(Wb + (size_t)row * IN_DIM + k0 + ac);
            Bs[0][ac + 0][row] = vb.x; Bs[0][ac + 1][row] = vb.y;
            Bs[0][ac + 2][row] = vb.z; Bs[0][ac + 3][row] = vb.w;
        }
    }
    __syncthreads();

    const int NSTEP = IN_DIM / BKK;   // 64
    for (int s = 0; s < NSTEP; ++s) {
        const int cur = s & 1;
        const int nxt = cur ^ 1;
        const bool more = (s + 1 < NSTEP);

        // issue next tile's global loads NOW; consumed only after compute
        float4 na0, na1, nb0, nb1;
        if (more) {
            const int k0 = (s + 1) * BKK;
            na0 = *(const float4*)(Xb + (size_t)(ar)      * IN_DIM + k0 + ac);
            na1 = *(const float4*)(Xb + (size_t)(ar + 64) * IN_DIM + k0 + ac);
            nb0 = *(const float4*)(Wb + (size_t)(ar)      * IN_DIM + k0 + ac);
            nb1 = *(const float4*)(Wb + (size_t)(ar + 64) * IN_DIM + k0 + ac);
        }

        // compute on current buffer (k order identical to v1 -> bit-identical C)
#pragma unroll
        for (int kk = 0; kk < BKK; ++kk) {
            float a[8], b[8];
            *(float4*)&a[0] = *(const float4*)&As[cur][kk][ty * 8];
            *(float4*)&a[4] = *(const float4*)&As[cur][kk][ty * 8 + 4];
            *(float4*)&b[0] = *(const float4*)&Bs[cur][kk][tx * 8];
            *(float4*)&b[4] = *(const float4*)&Bs[cur][kk][tx * 8 + 4];
#pragma unroll
            for (int i = 0; i < 8; ++i)
#pragma unroll
                for (int j = 0; j < 8; ++j)
                    acc[i][j] = fmaf(a[i], b[j], acc[i][j]);
        }

        if (more) {
            As[nxt][ac + 0][ar]      = na0.x; As[nxt][ac + 1][ar]      = na0.y;
            As[nxt][ac + 2][ar]      = na0.z; As[nxt][ac + 3][ar]      = na0.w;
            As[nxt][ac + 0][ar + 64] = na1.x; As[nxt][ac + 1][ar + 64] = na1.y;
            As[nxt][ac + 2][ar + 64] = na1.z; As[nxt][ac + 3][ar + 64] = na1.w;
            Bs[nxt][ac + 0][ar]      = nb0.x; Bs[nxt][ac + 1][ar]      = nb0.y;
            Bs[nxt][ac + 2][ar]      = nb0.z; Bs[nxt][ac + 3][ar]      = nb0.w;
            Bs[nxt][ac + 0][ar + 64] = nb1.x; Bs[nxt][ac + 1][ar + 64] = nb1.y;
            Bs[nxt][ac + 2][ar + 64] = nb1.z; Bs[nxt][ac + 3][ar + 64] = nb1.w;
        }
        __syncthreads();
    }

    const int col0 = bn * BN + tx * 8;
    float bv[8];
#pragma unroll
    for (int j = 0; j < 8; ++j) bv[j] = bias[col0 + j];
#pragma unroll
    for (int i = 0; i < 8; ++i) {
        const size_t rowoff = (size_t)(bm * BM + ty * 8 + i) * HID + col0;
        float4 o0, o1;
        o0.x = acc[i][0] + bv[0]; o0.y = acc[i][1] + bv[1];
        o0.z = acc[i][2] + bv[2]; o0.w = acc[i][3] + bv[3];
        o1.x = acc[i][4] + bv[4]; o1.y = acc[i][5] + bv[5];
        o1.z = acc[i][6] + bv[6]; o1.w = acc[i][7] + bv[7];
        *(float4*)(C + rowoff)     = o0;
        *(float4*)(C + rowoff + 4) = o1;
    }
}

// ---------------------------------------------------------------------------
// Kernel 2 (v2): per-row exact top-32 by |value|, radix select on abs bits.
// - row resident in registers (64 floats/thread), single global read + write
// - level 1 (exponent bits, hot) into 8 bank-padded histogram copies
// - bin selection via parallel 256-wide suffix scan (no serial t0 walk)
// Levels: bits 30:23 (256), 22:15 (256), 14:7 (256), 6:0 (128).
// ---------------------------------------------------------------------------
__global__ __launch_bounds__(256)
void topk_rows(float* __restrict__ E, int* __restrict__ idx_out,
               float* __restrict__ val_out)
{
    const int row = blockIdx.x;
    float* p = E + (size_t)row * HID;
    const int t = threadIdx.x;

    __shared__ unsigned h8[8][257];      // level-1 privatized copies (bank-spread)
    __shared__ unsigned hist[256];
    __shared__ unsigned scan[256];
    __shared__ unsigned s_prefix;
    __shared__ int s_rank, s_eq, s_cnt;

    // load entire row into registers (coalesced float4 per chunk)
    float4 v[16];
#pragma unroll
    for (int c = 0; c < 16; ++c)
        v[c] = *(const float4*)(p + (size_t)(c * 256 + t) * 4);

    for (int i = t; i < 8 * 257; i += 256) ((unsigned*)h8)[i] = 0u;
    if (t == 0) { s_rank = KSEL; s_prefix = 0u; s_eq = 0; s_cnt = 0; }
    __syncthreads();

    // ---- level 1: histogram exponent bits 30:23 into copy (t&7)
    unsigned* myh = h8[t & 7];
#pragma unroll
    for (int c = 0; c < 16; ++c) {
        const float vv[4] = {v[c].x, v[c].y, v[c].z, v[c].w};
#pragma unroll
        for (int j = 0; j < 4; ++j) {
            const unsigned k = __float_as_uint(vv[j]) & 0x7FFFFFFFu;
            atomicAdd(&myh[k >> 23], 1u);
        }
    }
    __syncthreads();

    const int psh_arr[4]  = {31, 23, 15, 7};   // prefix shift (31 => no prefix)
    const int sh_arr[4]   = {23, 15, 7, 0};    // bin shift
    const int nb_arr[4]   = {256, 256, 256, 128};
    const int bits_arr[4] = {8, 8, 8, 7};

    for (int lvl = 0; lvl < 4; ++lvl) {
        const int nb = nb_arr[lvl];
        const int r  = s_rank;                 // stable: last write was before a barrier
        const unsigned pfx = s_prefix;

        if (lvl == 0) {
            // merge the 8 privatized copies
            unsigned m = 0;
#pragma unroll
            for (int c = 0; c < 8; ++c) m += h8[c][t];
            hist[t] = m;
        } else {
            hist[t] = 0u;
            __syncthreads();
            const int psh = psh_arr[lvl];
            const int sh  = sh_arr[lvl];
#pragma unroll
            for (int c = 0; c < 16; ++c) {
                const float vv[4] = {v[c].x, v[c].y, v[c].z, v[c].w};
#pragma unroll
                for (int j = 0; j < 4; ++j) {
                    const unsigned k = __float_as_uint(vv[j]) & 0x7FFFFFFFu;
                    if ((k >> psh) == pfx)
                        atomicAdd(&hist[(k >> sh) & (unsigned)(nb - 1)], 1u);
                }
            }
        }
        __syncthreads();

        // parallel inclusive suffix scan over nb bins
        scan[t] = (t < nb) ? hist[t] : 0u;
        __syncthreads();
        for (int off = 1; off < nb; off <<= 1) {
            const unsigned add = (t + off < nb) ? scan[t + off] : 0u;
            __syncthreads();
            scan[t] += add;
            __syncthreads();
        }
        // exactly one thread owns the boundary bin
        if (t < nb && scan[t] >= (unsigned)r &&
            (t == nb - 1 || scan[t + 1] < (unsigned)r)) {
            s_rank   = r - (int)((t == nb - 1) ? 0u : scan[t + 1]);
            s_prefix = (pfx << bits_arr[lvl]) | (unsigned)t;
        }
        __syncthreads();
    }

    const unsigned vkey = s_prefix;   // exact 31-bit abs key of the 32nd largest
    const int eq_need   = s_rank;     // how many ==vkey elements to keep (>=1)

    // ---- final: mask in registers, write back, emit compact (idx,val) list
#pragma unroll
    for (int c = 0; c < 16; ++c) {
        const int i0 = (c * 256 + t) * 4;
        float vv[4] = {v[c].x, v[c].y, v[c].z, v[c].w};
#pragma unroll
        for (int j = 0; j < 4; ++j) {
            const unsigned k = __float_as_uint(vv[j]) & 0x7FFFFFFFu;
            bool keep = false;
            if (k > vkey) keep = true;
            else if (k == vkey) {
                const int slot = atomicAdd(&s_eq, 1);
                if (slot < eq_need) keep = true;
            }
            if (keep) {
                const int ls = atomicAdd(&s_cnt, 1);
                idx_out[row * KSEL + ls] = i0 + j;
                val_out[row * KSEL + ls] = vv[j];
            } else {
                vv[j] = 0.f;
            }
        }
        float4 o; o.x = vv[0]; o.y = vv[1]; o.z = vv[2]; o.w = vv[3];
        *(float4*)(p + i0) = o;
    }
}

// ---------------------------------------------------------------------------
// Kernel 3: transpose W_dec [1024,16384] -> WdT [16384,1024] (ws scratch)
// ---------------------------------------------------------------------------
__global__ __launch_bounds__(256)
void transpose_wdec(const float* __restrict__ Wd, float* __restrict__ WdT)
{
    __shared__ float tile[32][33];
    const int bx = blockIdx.x;           // along HID (512)
    const int by = blockIdx.y;           // along IN_DIM (32)
    const int t  = threadIdx.x;
    const int lx = t & 31, ly = t >> 5;  // 32 x 8
#pragma unroll
    for (int r = 0; r < 32; r += 8)
        tile[ly + r][lx] = Wd[(size_t)(by * 32 + ly + r) * HID + bx * 32 + lx];
    __syncthreads();
#pragma unroll
    for (int r = 0; r < 32; r += 8)
        WdT[(size_t)(bx * 32 + ly + r) * IN_DIM + by * 32 + lx] = tile[lx][ly + r];
}

// ---------------------------------------------------------------------------
// Kernel 4: sparse decode  decoded[b,:] = sum_i val_i * WdT[idx_i,:] + b_dec
// ---------------------------------------------------------------------------
__global__ __launch_bounds__(256)
void decode_rows(const float* __restrict__ WdT, const float* __restrict__ bd,
                 const int* __restrict__ idxs, const float* __restrict__ vals,
                 float* __restrict__ out)
{
    const int row = blockIdx.x;
    const int d   = threadIdx.x * 4;
    float4 acc = *(const float4*)(bd + d);
    for (int i = 0; i < KSEL; ++i) {
        const int   j = idxs[row * KSEL + i];
        const float v = vals[row * KSEL + i];
        const float4 w = *(const float4*)(WdT + (size_t)j * IN_DIM + d);
        acc.x = fmaf(v, w.x, acc.x);
        acc.y = fmaf(v, w.y, acc.y);
        acc.z = fmaf(v, w.z, acc.z);
        acc.w = fmaf(v, w.w, acc.w);
    }
    *(float4*)(out + (size_t)row * IN_DIM + d) = acc;
}

// Fallback decoder (no transposed copy available): strided W_dec reads.
__global__ __launch_bounds__(256)
void decode_rows_noT(const float* __restrict__ Wd, const float* __restrict__ bd,
                     const int* __restrict__ idxs, const float* __restrict__ vals,
                     float* __restrict__ out)
{
    const int row = blockIdx.x;
    const int d0  = threadIdx.x * 4;
    float acc[4];
#pragma unroll
    for (int q = 0; q < 4; ++q) acc[q] = bd[d0 + q];
    for (int i = 0; i < KSEL; ++i) {
        const int   j = idxs[row * KSEL + i];
        const float v = vals[row * KSEL + i];
#pragma unroll
        for (int q = 0; q < 4; ++q)
            acc[q] = fmaf(v, Wd[(size_t)(d0 + q) * HID + j], acc[q]);
    }
#pragma unroll
    for (int q = 0; q < 4; ++q) out[(size_t)row * IN_DIM + d0 + q] = acc[q];
}

// ---------------------------------------------------------------------------
extern "C" void kernel_launch(void* const* d_in, const int* in_sizes, int n_in,
                              void* d_out, int out_size, void* d_ws, size_t ws_size,
                              hipStream_t stream)
{
    const float* x     = (const float*)d_in[0];
    const float* W_enc = (const float*)d_in[1];
    const float* b_enc = (const float*)d_in[2];
    const float* W_dec = (const float*)d_in[3];
    const float* b_dec = (const float*)d_in[4];

    float* out     = (float*)d_out;
    float* sparse  = out;                                // [4096][16384]
    float* decoded = out + (size_t)BATCH * HID;          // [4096][1024]

    // ws layout: [idx list 512KB][val list 512KB][WdT 64MB]
    const size_t list_bytes = (size_t)BATCH * KSEL * 4;
    int*   idx_l = (int*)d_ws;
    float* val_l = (float*)((char*)d_ws + list_bytes);
    float* WdT   = (float*)((char*)d_ws + 2 * list_bytes);
    const bool have_wdt =
        ws_size >= 2 * list_bytes + (size_t)HID * IN_DIM * sizeof(float);

    // 1) encoder GEMM -> sparse region of d_out
    enc_gemm<<<dim3(HID / BN, BATCH / BM), 256, 0, stream>>>(x, W_enc, b_enc, sparse);

    // 2) per-row exact top-32 mask (in place) + compact lists
    topk_rows<<<BATCH, 256, 0, stream>>>(sparse, idx_l, val_l);

    // 3+4) decode
    if (have_wdt) {
        transpose_wdec<<<dim3(HID / 32, IN_DIM / 32), 256, 0, stream>>>(W_dec, WdT);
        decode_rows<<<BATCH, 256, 0, stream>>>(WdT, b_dec, idx_l, val_l, decoded);
    } else {
        decode_rows_noT<<<BATCH, 256, 0, stream>>>(W_dec, b_dec, idx_l, val_l, decoded);
    }
}

// Round 3
// 9055.691 us; speedup vs baseline: 3.3780x; 3.3780x over previous
//
#include <hip/hip_runtime.h>
#include <cstdint>
#include <cstddef>

#define BATCH   4096
#define IN_DIM  1024
#define HID     16384
#define KSEL    32

// ---------------------------------------------------------------------------
// Kernel 1: encoder GEMM  C[B,H] = X[B,D] @ W_enc[H,D]^T + b_enc
// fp32 vector GEMM, 128x128 tile, BK=16, 256 threads, 8x8 micro-tile.
// Double-buffered LDS + register prefetch, ONE barrier per K-step.
// __launch_bounds__(256,2): min-waves=2 -> 256-VGPR cap. (256,4) capped at
// 128 VGPRs and spilled acc[8][8] to scratch -> 77 GB writes, 19x slowdown
// (round-2 post-mortem). Do not raise the second arg.
// ---------------------------------------------------------------------------
#define BM 128
#define BN 128
#define BKK 16

__global__ __launch_bounds__(256, 2)
void enc_gemm(const float* __restrict__ X, const float* __restrict__ W,
              const float* __restrict__ bias, float* __restrict__ C)
{
    // +4 pad: keeps 16B alignment (132 = 33 float4) and staging stores 2-way (free).
    __shared__ float As[2][BKK][BM + 4];
    __shared__ float Bs[2][BKK][BN + 4];

    const int bn = blockIdx.x;   // HID/128 = 128
    const int bm = blockIdx.y;   // BATCH/128 = 32
    const int t  = threadIdx.x;
    const int tx = t & 15;       // 8 cols each
    const int ty = t >> 4;       // 8 rows each
    const int ar = t >> 2;       // staging row 0..63
    const int ac = (t & 3) << 2; // staging k-offset 0,4,8,12

    float acc[8][8];
#pragma unroll
    for (int i = 0; i < 8; ++i)
#pragma unroll
        for (int j = 0; j < 8; ++j) acc[i][j] = 0.f;

    const float* Xb = X + (size_t)(bm * BM) * IN_DIM;
    const float* Wb = W + (size_t)(bn * BN) * IN_DIM;

    // ---- prologue: stage tile 0 into buffer 0
    {
#pragma unroll
        for (int p = 0; p < 2; ++p) {
            const int row = ar + p * 64;
            const float4 va = *(const float4*)(Xb + (size_t)row * IN_DIM + ac);
            As[0][ac + 0][row] = va.x; As[0][ac + 1][row] = va.y;
            As[0][ac + 2][row] = va.z; As[0][ac + 3][row] = va.w;
            const float4 vb = *(const float4*)(Wb + (size_t)row * IN_DIM + ac);
            Bs[0][ac + 0][row] = vb.x; Bs[0][ac + 1][row] = vb.y;
            Bs[0][ac + 2][row] = vb.z; Bs[0][ac + 3][row] = vb.w;
        }
    }
    __syncthreads();

    const int NSTEP = IN_DIM / BKK;   // 64
    for (int s = 0; s < NSTEP; ++s) {
        const int cur = s & 1;
        const int nxt = cur ^ 1;
        const bool more = (s + 1 < NSTEP);

        // issue next tile's global loads NOW; consumed after compute
        float4 na0, na1, nb0, nb1;
        if (more) {
            const int k0 = (s + 1) * BKK;
            na0 = *(const float4*)(Xb + (size_t)(ar)      * IN_DIM + k0 + ac);
            na1 = *(const float4*)(Xb + (size_t)(ar + 64) * IN_DIM + k0 + ac);
            nb0 = *(const float4*)(Wb + (size_t)(ar)      * IN_DIM + k0 + ac);
            nb1 = *(const float4*)(Wb + (size_t)(ar + 64) * IN_DIM + k0 + ac);
        }

        // compute on current buffer (k order identical across versions)
#pragma unroll
        for (int kk = 0; kk < BKK; ++kk) {
            float a[8], b[8];
            *(float4*)&a[0] = *(const float4*)&As[cur][kk][ty * 8];
            *(float4*)&a[4] = *(const float4*)&As[cur][kk][ty * 8 + 4];
            *(float4*)&b[0] = *(const float4*)&Bs[cur][kk][tx * 8];
            *(float4*)&b[4] = *(const float4*)&Bs[cur][kk][tx * 8 + 4];
#pragma unroll
            for (int i = 0; i < 8; ++i)
#pragma unroll
                for (int j = 0; j < 8; ++j)
                    acc[i][j] = fmaf(a[i], b[j], acc[i][j]);
        }

        if (more) {
            As[nxt][ac + 0][ar]      = na0.x; As[nxt][ac + 1][ar]      = na0.y;
            As[nxt][ac + 2][ar]      = na0.z; As[nxt][ac + 3][ar]      = na0.w;
            As[nxt][ac + 0][ar + 64] = na1.x; As[nxt][ac + 1][ar + 64] = na1.y;
            As[nxt][ac + 2][ar + 64] = na1.z; As[nxt][ac + 3][ar + 64] = na1.w;
            Bs[nxt][ac + 0][ar]      = nb0.x; Bs[nxt][ac + 1][ar]      = nb0.y;
            Bs[nxt][ac + 2][ar]      = nb0.z; Bs[nxt][ac + 3][ar]      = nb0.w;
            Bs[nxt][ac + 0][ar + 64] = nb1.x; Bs[nxt][ac + 1][ar + 64] = nb1.y;
            Bs[nxt][ac + 2][ar + 64] = nb1.z; Bs[nxt][ac + 3][ar + 64] = nb1.w;
        }
        __syncthreads();
    }

    const int col0 = bn * BN + tx * 8;
    float bv[8];
#pragma unroll
    for (int j = 0; j < 8; ++j) bv[j] = bias[col0 + j];
#pragma unroll
    for (int i = 0; i < 8; ++i) {
        const size_t rowoff = (size_t)(bm * BM + ty * 8 + i) * HID + col0;
        float4 o0, o1;
        o0.x = acc[i][0] + bv[0]; o0.y = acc[i][1] + bv[1];
        o0.z = acc[i][2] + bv[2]; o0.w = acc[i][3] + bv[3];
        o1.x = acc[i][4] + bv[4]; o1.y = acc[i][5] + bv[5];
        o1.z = acc[i][6] + bv[6]; o1.w = acc[i][7] + bv[7];
        *(float4*)(C + rowoff)     = o0;
        *(float4*)(C + rowoff + 4) = o1;
    }
}

// ---------------------------------------------------------------------------
// Kernel 2 (v3): per-row exact top-32 by |value|, 4-level radix select on
// the abs bit pattern. No register residency (v2 spilled); rows are re-read
// from L1/L2/LLC (64 KB/row stays hot). Level 0 (exponent, hot bins) goes
// into 16 privatized histogram copies; bin selection by parallel suffix scan.
// Levels: bits 30:23 (256), 22:15 (256), 14:7 (256), 6:0 (128).
// ---------------------------------------------------------------------------
__global__ __launch_bounds__(256)
void topk_rows(float* __restrict__ E, int* __restrict__ idx_out,
               float* __restrict__ val_out)
{
    const int row = blockIdx.x;
    float* p = E + (size_t)row * HID;
    const int t = threadIdx.x;

    __shared__ unsigned h16[16][257];    // level-0 privatized copies (16.4 KB)
    __shared__ unsigned hist[256];
    __shared__ unsigned scan[256];
    __shared__ unsigned s_prefix;
    __shared__ int s_rank, s_eq, s_cnt;

    for (int i = t; i < 16 * 257; i += 256) ((unsigned*)h16)[i] = 0u;
    if (t == 0) { s_rank = KSEL; s_prefix = 0u; s_eq = 0; s_cnt = 0; }
    __syncthreads();

    // ---- level 0: histogram of exponent bits 30:23 into copy (t & 15)
    unsigned* myh = h16[t & 15];
    for (int c = 0; c < 16; ++c) {
        const float4 v = *(const float4*)(p + (size_t)(c * 256 + t) * 4);
        const float vv[4] = {v.x, v.y, v.z, v.w};
#pragma unroll
        for (int j = 0; j < 4; ++j) {
            const unsigned k = __float_as_uint(vv[j]) & 0x7FFFFFFFu;
            atomicAdd(&myh[k >> 23], 1u);
        }
    }
    __syncthreads();

    const int psh_arr[4]  = {31, 23, 15, 7};   // prefix shift (31 => match-all)
    const int sh_arr[4]   = {23, 15, 7, 0};    // bin shift
    const int nb_arr[4]   = {256, 256, 256, 128};
    const int bits_arr[4] = {8, 8, 8, 7};

#pragma unroll
    for (int lvl = 0; lvl < 4; ++lvl) {
        const int nb = nb_arr[lvl];
        const int r  = s_rank;                 // write->barrier->read: safe
        const unsigned pfx = s_prefix;

        if (lvl == 0) {
            unsigned m = 0;
#pragma unroll
            for (int c = 0; c < 16; ++c) m += h16[c][t];
            hist[t] = m;
        } else {
            hist[t] = 0u;
            __syncthreads();
            const int psh = psh_arr[lvl];
            const int sh  = sh_arr[lvl];
            for (int c = 0; c < 16; ++c) {
                const float4 v = *(const float4*)(p + (size_t)(c * 256 + t) * 4);
                const float vv[4] = {v.x, v.y, v.z, v.w};
#pragma unroll
                for (int j = 0; j < 4; ++j) {
                    const unsigned k = __float_as_uint(vv[j]) & 0x7FFFFFFFu;
                    if ((k >> psh) == pfx)     // mantissa bins ~uniform: low contention
                        atomicAdd(&hist[(k >> sh) & (unsigned)(nb - 1)], 1u);
                }
            }
        }
        __syncthreads();

        // parallel inclusive SUFFIX scan over nb bins (monotone nonincreasing in t)
        scan[t] = (t < nb) ? hist[t] : 0u;
        __syncthreads();
        for (int off = 1; off < nb; off <<= 1) {
            const unsigned add = (t + off < nb) ? scan[t + off] : 0u;
            __syncthreads();
            scan[t] += add;
            __syncthreads();
        }
        // exactly one thread owns the boundary bin
        if (t < nb && scan[t] >= (unsigned)r &&
            (t == nb - 1 || scan[t + 1] < (unsigned)r)) {
            s_rank   = r - (int)((t == nb - 1) ? 0u : scan[t + 1]);
            s_prefix = (pfx << bits_arr[lvl]) | (unsigned)t;
        }
        __syncthreads();
    }

    const unsigned vkey = s_prefix;   // exact 31-bit abs key of the 32nd largest
    const int eq_need   = s_rank;     // how many ==vkey elements to keep (>=1)

    // ---- final pass: mask in place, emit compact (idx,val) list
    for (int c = 0; c < 16; ++c) {
        const int i0 = (c * 256 + t) * 4;
        float4 v = *(const float4*)(p + i0);
        float vv[4] = {v.x, v.y, v.z, v.w};
#pragma unroll
        for (int j = 0; j < 4; ++j) {
            const unsigned k = __float_as_uint(vv[j]) & 0x7FFFFFFFu;
            bool keep = false;
            if (k > vkey) keep = true;
            else if (k == vkey) {
                const int slot = atomicAdd(&s_eq, 1);
                if (slot < eq_need) keep = true;
            }
            if (keep) {
                const int ls = atomicAdd(&s_cnt, 1);
                idx_out[row * KSEL + ls] = i0 + j;
                val_out[row * KSEL + ls] = vv[j];
            } else {
                vv[j] = 0.f;
            }
        }
        float4 o; o.x = vv[0]; o.y = vv[1]; o.z = vv[2]; o.w = vv[3];
        *(float4*)(p + i0) = o;
    }
}

// ---------------------------------------------------------------------------
// Kernel 3: transpose W_dec [1024,16384] -> WdT [16384,1024] (ws scratch)
// ---------------------------------------------------------------------------
__global__ __launch_bounds__(256)
void transpose_wdec(const float* __restrict__ Wd, float* __restrict__ WdT)
{
    __shared__ float tile[32][33];
    const int bx = blockIdx.x;           // along HID (512)
    const int by = blockIdx.y;           // along IN_DIM (32)
    const int t  = threadIdx.x;
    const int lx = t & 31, ly = t >> 5;  // 32 x 8
#pragma unroll
    for (int r = 0; r < 32; r += 8)
        tile[ly + r][lx] = Wd[(size_t)(by * 32 + ly + r) * HID + bx * 32 + lx];
    __syncthreads();
#pragma unroll
    for (int r = 0; r < 32; r += 8)
        WdT[(size_t)(bx * 32 + ly + r) * IN_DIM + by * 32 + lx] = tile[lx][ly + r];
}

// ---------------------------------------------------------------------------
// Kernel 4: sparse decode  decoded[b,:] = sum_i val_i * WdT[idx_i,:] + b_dec
// ---------------------------------------------------------------------------
__global__ __launch_bounds__(256)
void decode_rows(const float* __restrict__ WdT, const float* __restrict__ bd,
                 const int* __restrict__ idxs, const float* __restrict__ vals,
                 float* __restrict__ out)
{
    const int row = blockIdx.x;
    const int d   = threadIdx.x * 4;
    float4 acc = *(const float4*)(bd + d);
    for (int i = 0; i < KSEL; ++i) {
        const int   j = idxs[row * KSEL + i];
        const float v = vals[row * KSEL + i];
        const float4 w = *(const float4*)(WdT + (size_t)j * IN_DIM + d);
        acc.x = fmaf(v, w.x, acc.x);
        acc.y = fmaf(v, w.y, acc.y);
        acc.z = fmaf(v, w.z, acc.z);
        acc.w = fmaf(v, w.w, acc.w);
    }
    *(float4*)(out + (size_t)row * IN_DIM + d) = acc;
}

// Fallback decoder (no transposed copy available): strided W_dec reads.
__global__ __launch_bounds__(256)
void decode_rows_noT(const float* __restrict__ Wd, const float* __restrict__ bd,
                     const int* __restrict__ idxs, const float* __restrict__ vals,
                     float* __restrict__ out)
{
    const int row = blockIdx.x;
    const int d0  = threadIdx.x * 4;
    float acc[4];
#pragma unroll
    for (int q = 0; q < 4; ++q) acc[q] = bd[d0 + q];
    for (int i = 0; i < KSEL; ++i) {
        const int   j = idxs[row * KSEL + i];
        const float v = vals[row * KSEL + i];
#pragma unroll
        for (int q = 0; q < 4; ++q)
            acc[q] = fmaf(v, Wd[(size_t)(d0 + q) * HID + j], acc[q]);
    }
#pragma unroll
    for (int q = 0; q < 4; ++q) out[(size_t)row * IN_DIM + d0 + q] = acc[q];
}

// ---------------------------------------------------------------------------
extern "C" void kernel_launch(void* const* d_in, const int* in_sizes, int n_in,
                              void* d_out, int out_size, void* d_ws, size_t ws_size,
                              hipStream_t stream)
{
    const float* x     = (const float*)d_in[0];
    const float* W_enc = (const float*)d_in[1];
    const float* b_enc = (const float*)d_in[2];
    const float* W_dec = (const float*)d_in[3];
    const float* b_dec = (const float*)d_in[4];

    float* out     = (float*)d_out;
    float* sparse  = out;                                // [4096][16384]
    float* decoded = out + (size_t)BATCH * HID;          // [4096][1024]

    // ws layout: [idx list 512KB][val list 512KB][WdT 64MB]
    const size_t list_bytes = (size_t)BATCH * KSEL * 4;
    int*   idx_l = (int*)d_ws;
    float* val_l = (float*)((char*)d_ws + list_bytes);
    float* WdT   = (float*)((char*)d_ws + 2 * list_bytes);
    const bool have_wdt =
        ws_size >= 2 * list_bytes + (size_t)HID * IN_DIM * sizeof(float);

    // 1) encoder GEMM -> sparse region of d_out
    enc_gemm<<<dim3(HID / BN, BATCH / BM), 256, 0, stream>>>(x, W_enc, b_enc, sparse);

    // 2) per-row exact top-32 mask (in place) + compact lists
    topk_rows<<<BATCH, 256, 0, stream>>>(sparse, idx_l, val_l);

    // 3+4) decode
    if (have_wdt) {
        transpose_wdec<<<dim3(HID / 32, IN_DIM / 32), 256, 0, stream>>>(W_dec, WdT);
        decode_rows<<<BATCH, 256, 0, stream>>>(WdT, b_dec, idx_l, val_l, decoded);
    } else {
        decode_rows_noT<<<BATCH, 256, 0, stream>>>(W_dec, b_dec, idx_l, val_l, decoded);
    }
}

// Round 5
// 2174.446 us; speedup vs baseline: 14.0680x; 4.1646x over previous
//
#include <hip/hip_runtime.h>
#include <cstdint>
#include <cstddef>

#define BATCH   4096
#define IN_DIM  1024
#define HID     16384
#define KSEL    32

// ---------------------------------------------------------------------------
// Kernel 1: encoder GEMM  C[B,H] = X[B,D] @ W_enc[H,D]^T + b_enc
// fp32, 128x128 tile, BK=32, 256 threads, 8x8 micro-tile.
// NUMERICS CONTRACT (do not change): per output element, fmaf over k in
// strictly ascending order with a single accumulator, then + bias. This is
// bit-identical to the round-1 kernel that passes validation. Top-k rank-32
// boundary gaps are ~0.007; any reordering (MFMA bf16x3 in r4: absmax 4.31,
// or k-splitting) flips selections vs the np reference. MFMA is unusable here.
//
// Staging: global_load_lds width=16 into ROW-MAJOR LDS tiles, 16B chunks
// XOR-swizzled by ((row>>3)&7) so compute ds_read_b128 is conflict-free.
// No register prefetch: r2/r3 showed prefetch regs balloon live ranges and
// spill acc[8][8] to scratch (77GB/28GB writes). Keep staging register-free.
// ---------------------------------------------------------------------------
#define BKK 32

__global__ __launch_bounds__(256, 2)
void enc_gemm(const float* __restrict__ X, const float* __restrict__ W,
              const float* __restrict__ bias, float* __restrict__ C)
{
    __shared__ __align__(16) float As[128 * BKK];   // 16 KB, row-major, swizzled
    __shared__ __align__(16) float Bs[128 * BKK];

    const int bn = blockIdx.x;   // HID/128 = 128 (fast dim, shares A via cache)
    const int bm = blockIdx.y;   // BATCH/128 = 32
    const int t  = threadIdx.x;
    const int tx = t & 15;       // 8 cols each
    const int ty = t >> 4;       // 8 rows each

    float acc[8][8];
#pragma unroll
    for (int i = 0; i < 8; ++i)
#pragma unroll
        for (int j = 0; j < 8; ++j) acc[i][j] = 0.f;

    const float* Xb = X + (size_t)(bm * 128) * IN_DIM;
    const float* Wb = W + (size_t)(bn * 128) * IN_DIM;

    const int aswz = ty & 7;     // A-read swizzle key ((m>>3)&7 = ty&7)
    const int bswz = tx & 7;     // B-read swizzle key ((n>>3)&7 = tx&7)

    for (int k0 = 0; k0 < IN_DIM; k0 += BKK) {
        // ---- stage 128x32 A and B tiles: 4 x 16B per thread per matrix.
        // LDS slot s holds row m = s>>3, global 16B-chunk (s&7)^((m>>3)&7).
        // Lane-contiguous LDS dst (s*16B) satisfies the global_load_lds
        // wave-uniform-base + lane*16 rule.
#pragma unroll
        for (int q = 0; q < 4; ++q) {
            const int s  = q * 256 + t;           // 0..1023
            const int m  = s >> 3;                // 0..127
            const int gc = (s & 7) ^ ((m >> 3) & 7);
            __builtin_amdgcn_global_load_lds(
                (const __attribute__((address_space(1))) void*)(Xb + (size_t)m * IN_DIM + k0 + gc * 4),
                (__attribute__((address_space(3))) void*)(As + s * 4), 16, 0, 0);
            __builtin_amdgcn_global_load_lds(
                (const __attribute__((address_space(1))) void*)(Wb + (size_t)m * IN_DIM + k0 + gc * 4),
                (__attribute__((address_space(3))) void*)(Bs + s * 4), 16, 0, 0);
        }
        __syncthreads();   // drains vmcnt (global_load_lds) before reads

        // ---- compute: 8 groups of 4 consecutive k, components in order
#pragma unroll
        for (int kq = 0; kq < 8; ++kq) {
            float4 a4[8], b4[8];
#pragma unroll
            for (int i = 0; i < 8; ++i)
                a4[i] = *(const float4*)(As + (ty * 8 + i) * BKK + ((kq ^ aswz) * 4));
#pragma unroll
            for (int j = 0; j < 8; ++j)
                b4[j] = *(const float4*)(Bs + (tx * 8 + j) * BKK + ((kq ^ bswz) * 4));
            // k ascending: c = 0,1,2,3  (bit-identical chain to round-1 kernel)
#pragma unroll
            for (int i = 0; i < 8; ++i)
#pragma unroll
                for (int j = 0; j < 8; ++j)
                    acc[i][j] = fmaf(a4[i].x, b4[j].x, acc[i][j]);
#pragma unroll
            for (int i = 0; i < 8; ++i)
#pragma unroll
                for (int j = 0; j < 8; ++j)
                    acc[i][j] = fmaf(a4[i].y, b4[j].y, acc[i][j]);
#pragma unroll
            for (int i = 0; i < 8; ++i)
#pragma unroll
                for (int j = 0; j < 8; ++j)
                    acc[i][j] = fmaf(a4[i].z, b4[j].z, acc[i][j]);
#pragma unroll
            for (int i = 0; i < 8; ++i)
#pragma unroll
                for (int j = 0; j < 8; ++j)
                    acc[i][j] = fmaf(a4[i].w, b4[j].w, acc[i][j]);
        }
        __syncthreads();
    }

    const int col0 = bn * 128 + tx * 8;
    float bv[8];
#pragma unroll
    for (int j = 0; j < 8; ++j) bv[j] = bias[col0 + j];
#pragma unroll
    for (int i = 0; i < 8; ++i) {
        const size_t rowoff = (size_t)(bm * 128 + ty * 8 + i) * HID + col0;
        float4 o0, o1;
        o0.x = acc[i][0] + bv[0]; o0.y = acc[i][1] + bv[1];
        o0.z = acc[i][2] + bv[2]; o0.w = acc[i][3] + bv[3];
        o1.x = acc[i][4] + bv[4]; o1.y = acc[i][5] + bv[5];
        o1.z = acc[i][6] + bv[6]; o1.w = acc[i][7] + bv[7];
        *(float4*)(C + rowoff)     = o0;
        *(float4*)(C + rowoff + 4) = o1;
    }
}

// ---------------------------------------------------------------------------
// Kernel 2 (v4): per-row exact top-32 by |value|, 4-level radix select on
// abs bit pattern. Row cached in LDS (64 KB) -> global traffic = 1 read +
// 1 write. Suffix "scan" via wave shuffles (no LDS scan array / barriers).
// Levels: bits 30:23 (256), 22:15 (256), 14:7 (256), 6:0 (128).
// ---------------------------------------------------------------------------
__global__ __launch_bounds__(256)
void topk_rows(float* __restrict__ E, int* __restrict__ idx_out,
               float* __restrict__ val_out)
{
    const int row = blockIdx.x;
    float* p = E + (size_t)row * HID;
    const int t    = threadIdx.x;
    const int lane = t & 63;
    const int wid  = t >> 6;

    __shared__ __align__(16) float row_s[HID];   // 64 KB row cache
    __shared__ unsigned h8[8][257];              // lvl-0 privatized hists
    __shared__ unsigned hist[256];
    __shared__ unsigned wsum[4];
    __shared__ unsigned s_prefix;
    __shared__ int s_rank, s_eq, s_cnt;

    // async-load the whole row into LDS (lane-contiguous 16B chunks)
#pragma unroll
    for (int c = 0; c < 16; ++c) {
        const int s = c * 256 + t;
        __builtin_amdgcn_global_load_lds(
            (const __attribute__((address_space(1))) void*)(p + (size_t)s * 4),
            (__attribute__((address_space(3))) void*)(row_s + s * 4), 16, 0, 0);
    }
    for (int i = t; i < 8 * 257; i += 256) ((unsigned*)h8)[i] = 0u;
    if (t == 0) { s_rank = KSEL; s_prefix = 0u; s_eq = 0; s_cnt = 0; }
    __syncthreads();

    // ---- level 0: exponent-byte histogram into 8 privatized copies
    unsigned* myh = h8[t & 7];
#pragma unroll
    for (int c = 0; c < 16; ++c) {
        const float4 v = *(const float4*)(row_s + (c * 256 + t) * 4);
        const float vv[4] = {v.x, v.y, v.z, v.w};
#pragma unroll
        for (int j = 0; j < 4; ++j)
            atomicAdd(&myh[(__float_as_uint(vv[j]) & 0x7FFFFFFFu) >> 23], 1u);
    }
    __syncthreads();

    const int psh_arr[4]  = {31, 23, 15, 7};
    const int sh_arr[4]   = {23, 15, 7, 0};
    const unsigned msk[4] = {255u, 255u, 255u, 127u};
    const int bits_arr[4] = {8, 8, 8, 7};

#pragma unroll
    for (int lvl = 0; lvl < 4; ++lvl) {
        const int r = s_rank;
        const unsigned pfx = s_prefix;

        unsigned mycnt;
        if (lvl == 0) {
            unsigned m = 0;
#pragma unroll
            for (int c = 0; c < 8; ++c) m += h8[c][t];
            mycnt = m;                       // own bin, no barrier needed
        } else {
            hist[t] = 0u;
            __syncthreads();
            const int psh = psh_arr[lvl];
            const int sh  = sh_arr[lvl];
#pragma unroll
            for (int c = 0; c < 16; ++c) {
                const float4 v = *(const float4*)(row_s + (c * 256 + t) * 4);
                const float vv[4] = {v.x, v.y, v.z, v.w};
#pragma unroll
                for (int j = 0; j < 4; ++j) {
                    const unsigned k = __float_as_uint(vv[j]) & 0x7FFFFFFFu;
                    if ((k >> psh) == pfx)   // few matches: contention trivial
                        atomicAdd(&hist[(k >> sh) & msk[lvl]], 1u);
                }
            }
            __syncthreads();
            mycnt = hist[t];
        }

        // wave-level inclusive suffix scan of bin counts (bin index = t)
        unsigned sv = mycnt;
#pragma unroll
        for (int off = 1; off < 64; off <<= 1) {
            const unsigned u = __shfl_down(sv, off, 64);
            sv += (lane + off < 64) ? u : 0u;
        }
        if (lane == 0) wsum[wid] = sv;       // this wave's 64-bin total
        __syncthreads();
        unsigned above = 0;
        for (int ww = wid + 1; ww < 4; ++ww) above += wsum[ww];
        const unsigned suff  = sv + above;   // sum of bins >= t
        const unsigned suffn = suff - mycnt; // sum of bins >  t
        if (suff >= (unsigned)r && suffn < (unsigned)r) {  // exactly one thread
            s_rank   = r - (int)suffn;
            s_prefix = (pfx << bits_arr[lvl]) | (unsigned)t;
        }
        __syncthreads();
    }

    const unsigned vkey = s_prefix;   // exact 31-bit abs key of the 32nd largest
    const int eq_need   = s_rank;     // how many ==vkey elements to keep (>=1)

    // ---- final: mask from LDS, write global row + compact (idx,val) lists
#pragma unroll
    for (int c = 0; c < 16; ++c) {
        const int i0 = (c * 256 + t) * 4;
        const float4 v = *(const float4*)(row_s + i0);
        float vv[4] = {v.x, v.y, v.z, v.w};
#pragma unroll
        for (int j = 0; j < 4; ++j) {
            const unsigned k = __float_as_uint(vv[j]) & 0x7FFFFFFFu;
            bool keep = false;
            if (k > vkey) keep = true;
            else if (k == vkey) {
                const int slot = atomicAdd(&s_eq, 1);
                if (slot < eq_need) keep = true;
            }
            if (keep) {
                const int ls = atomicAdd(&s_cnt, 1);
                idx_out[row * KSEL + ls] = i0 + j;
                val_out[row * KSEL + ls] = vv[j];
            } else {
                vv[j] = 0.f;
            }
        }
        float4 o; o.x = vv[0]; o.y = vv[1]; o.z = vv[2]; o.w = vv[3];
        *(float4*)(p + i0) = o;
    }
}

// ---------------------------------------------------------------------------
// Kernel 3: transpose W_dec [1024,16384] -> WdT [16384,1024] (ws scratch)
// ---------------------------------------------------------------------------
__global__ __launch_bounds__(256)
void transpose_wdec(const float* __restrict__ Wd, float* __restrict__ WdT)
{
    __shared__ float tile[32][33];
    const int bx = blockIdx.x;
    const int by = blockIdx.y;
    const int t  = threadIdx.x;
    const int lx = t & 31, ly = t >> 5;
#pragma unroll
    for (int r = 0; r < 32; r += 8)
        tile[ly + r][lx] = Wd[(size_t)(by * 32 + ly + r) * HID + bx * 32 + lx];
    __syncthreads();
#pragma unroll
    for (int r = 0; r < 32; r += 8)
        WdT[(size_t)(bx * 32 + ly + r) * IN_DIM + by * 32 + lx] = tile[lx][ly + r];
}

// ---------------------------------------------------------------------------
// Kernel 4: sparse decode  decoded[b,:] = sum_i val_i * WdT[idx_i,:] + b_dec
// ---------------------------------------------------------------------------
__global__ __launch_bounds__(256)
void decode_rows(const float* __restrict__ WdT, const float* __restrict__ bd,
                 const int* __restrict__ idxs, const float* __restrict__ vals,
                 float* __restrict__ out)
{
    const int row = blockIdx.x;
    const int d   = threadIdx.x * 4;
    float4 acc = *(const float4*)(bd + d);
    for (int i = 0; i < KSEL; ++i) {
        const int   j = idxs[row * KSEL + i];
        const float v = vals[row * KSEL + i];
        const float4 w = *(const float4*)(WdT + (size_t)j * IN_DIM + d);
        acc.x = fmaf(v, w.x, acc.x);
        acc.y = fmaf(v, w.y, acc.y);
        acc.z = fmaf(v, w.z, acc.z);
        acc.w = fmaf(v, w.w, acc.w);
    }
    *(float4*)(out + (size_t)row * IN_DIM + d) = acc;
}

__global__ __launch_bounds__(256)
void decode_rows_noT(const float* __restrict__ Wd, const float* __restrict__ bd,
                     const int* __restrict__ idxs, const float* __restrict__ vals,
                     float* __restrict__ out)
{
    const int row = blockIdx.x;
    const int d0  = threadIdx.x * 4;
    float acc[4];
#pragma unroll
    for (int q = 0; q < 4; ++q) acc[q] = bd[d0 + q];
    for (int i = 0; i < KSEL; ++i) {
        const int   j = idxs[row * KSEL + i];
        const float v = vals[row * KSEL + i];
#pragma unroll
        for (int q = 0; q < 4; ++q)
            acc[q] = fmaf(v, Wd[(size_t)(d0 + q) * HID + j], acc[q]);
    }
#pragma unroll
    for (int q = 0; q < 4; ++q) out[(size_t)row * IN_DIM + d0 + q] = acc[q];
}

// ---------------------------------------------------------------------------
extern "C" void kernel_launch(void* const* d_in, const int* in_sizes, int n_in,
                              void* d_out, int out_size, void* d_ws, size_t ws_size,
                              hipStream_t stream)
{
    const float* x     = (const float*)d_in[0];
    const float* W_enc = (const float*)d_in[1];
    const float* b_enc = (const float*)d_in[2];
    const float* W_dec = (const float*)d_in[3];
    const float* b_dec = (const float*)d_in[4];

    float* out     = (float*)d_out;
    float* sparse  = out;                                // [4096][16384]
    float* decoded = out + (size_t)BATCH * HID;          // [4096][1024]

    // ws layout: [idx list 512KB][val list 512KB][WdT 64MB]
    const size_t list_bytes = (size_t)BATCH * KSEL * 4;
    const size_t wdt_bytes  = (size_t)HID * IN_DIM * 4;
    int*   idx_l = (int*)d_ws;
    float* val_l = (float*)((char*)d_ws + list_bytes);
    float* WdT   = (float*)((char*)d_ws + 2 * list_bytes);
    const bool have_wdt = ws_size >= 2 * list_bytes + wdt_bytes;

    enc_gemm<<<dim3(HID / 128, BATCH / 128), 256, 0, stream>>>(x, W_enc, b_enc, sparse);

    topk_rows<<<BATCH, 256, 0, stream>>>(sparse, idx_l, val_l);

    if (have_wdt) {
        transpose_wdec<<<dim3(HID / 32, IN_DIM / 32), 256, 0, stream>>>(W_dec, WdT);
        decode_rows<<<BATCH, 256, 0, stream>>>(WdT, b_dec, idx_l, val_l, decoded);
    } else {
        decode_rows_noT<<<BATCH, 256, 0, stream>>>(W_dec, b_dec, idx_l, val_l, decoded);
    }
}